// Round 1
// baseline (985.406 us; speedup 1.0000x reference)
//
#include <hip/hip_runtime.h>
#include <hip/hip_bf16.h>
#include <math.h>

#define BSZ 8
#define NSEQ 2048
#define DD 128
#define ROWS (BSZ*NSEQ)
#define EPS 1e-5f

// ---------- shared helpers ----------

// Stage a 128x128 row-major weight into LDS with rotation swizzle:
// Wl[o*128 + ((i+o)&127)] = W[o*128+i]. Read pattern (fixed i, o=lane)
// hits banks (i+o)%32 -> 2 lanes/bank (free).
__device__ __forceinline__ void stageW(const float* __restrict__ W, float* Wl, int tid){
    for (int idx = tid; idx < 128*128; idx += 256){
        int o = idx >> 7, i = idx & 127;
        Wl[o*128 + ((i+o)&127)] = W[idx];
    }
}

// out[o] = sum_i in[i]*W[o][i], in held as 2 regs/lane (in0=in[lane], in1=in[lane+64])
__device__ __forceinline__ void gemm128(const float* Wl, float in0, float in1, int lane,
                                        float& out0, float& out1){
    float acc0 = 0.f, acc1 = 0.f;
    const int o0 = lane, o1 = lane + 64;
    #pragma unroll 8
    for (int i = 0; i < 64; ++i){
        float v = __shfl(in0, i, 64);
        acc0 += v * Wl[o0*128 + ((i+o0)&127)];
        acc1 += v * Wl[o1*128 + ((i+o1)&127)];
    }
    #pragma unroll 8
    for (int i = 64; i < 128; ++i){
        float v = __shfl(in1, i-64, 64);
        acc0 += v * Wl[o0*128 + ((i+o0)&127)];
        acc1 += v * Wl[o1*128 + ((i+o1)&127)];
    }
    out0 = acc0; out1 = acc1;
}

__device__ __forceinline__ float waveSum(float v){
    #pragma unroll
    for (int m = 32; m; m >>= 1) v += __shfl_xor(v, m, 64);
    return v;
}

// ---------- kernel 1: x = x_in + enc@Wenc^T + b ; xn = LN1(x) ----------
__global__ __launch_bounds__(256) void k_enc_ln1(
    const float* __restrict__ xin, const float* __restrict__ enc,
    const float* __restrict__ Wenc, const float* __restrict__ benc,
    const float* __restrict__ g1, const float* __restrict__ b1,
    float* __restrict__ x, float* __restrict__ xn)
{
    __shared__ float Wl[128*128];
    const int tid = threadIdx.x;
    stageW(Wenc, Wl, tid);
    const int wv = tid >> 6, lane = tid & 63;
    const int row = blockIdx.x * 4 + wv;
    const float e0 = enc[row*128 + lane];
    const float e1 = enc[row*128 + lane + 64];
    __syncthreads();
    float a0, a1;
    gemm128(Wl, e0, e1, lane, a0, a1);
    const int d0 = lane, d1 = lane + 64;
    float v0 = xin[row*128 + d0] + a0 + benc[d0];
    float v1 = xin[row*128 + d1] + a1 + benc[d1];
    x[row*128 + d0] = v0; x[row*128 + d1] = v1;
    float mean = waveSum(v0 + v1) * (1.f/128.f);
    float c0 = v0 - mean, c1 = v1 - mean;
    float var = waveSum(c0*c0 + c1*c1) * (1.f/128.f);
    float rstd = rsqrtf(var + EPS);
    xn[row*128 + d0] = c0*rstd*g1[d0] + b1[d0];
    xn[row*128 + d1] = c1*rstd*g1[d1] + b1[d1];
}

// ---------- kernel 2: h = xn@W^T ; s1 = h.a1 ; s2 = h.a2 ----------
__global__ __launch_bounds__(256) void k_h(
    const float* __restrict__ xn, const float* __restrict__ W,
    const float* __restrict__ aw,
    float* __restrict__ h, float* __restrict__ s1, float* __restrict__ s2)
{
    __shared__ float Wl[128*128];
    const int tid = threadIdx.x;
    stageW(W, Wl, tid);
    const int wv = tid >> 6, lane = tid & 63;
    const int row = blockIdx.x * 4 + wv;
    const float i0 = xn[row*128 + lane];
    const float i1 = xn[row*128 + lane + 64];
    __syncthreads();
    float a0, a1;
    gemm128(Wl, i0, i1, lane, a0, a1);
    h[row*128 + lane] = a0; h[row*128 + lane + 64] = a1;
    float p1 = a0*aw[lane] + a1*aw[lane+64];
    float p2 = a0*aw[128+lane] + a1*aw[128+lane+64];
    p1 = waveSum(p1); p2 = waveSum(p2);
    if (lane == 0){ s1[row] = p1; s2[row] = p2; }
}

// ---------- kernel 3: per-batch sort of s2 (desc) + scalar prefix scans + E/F ----------
__global__ __launch_bounds__(1024) void k_sort(
    const float* __restrict__ s2g,
    float* __restrict__ s2s, int* __restrict__ perm,
    float* __restrict__ SEx, float* __restrict__ SFx,
    float* __restrict__ Eo, float* __restrict__ Fo,
    float* __restrict__ M2b)
{
    __shared__ float val[2048];
    __shared__ int   idx[2048];
    __shared__ float sa[2048], sb[2048], fa[2048], fb[2048];
    const int b = blockIdx.x, t = threadIdx.x;
    for (int c = t; c < 2048; c += 1024){ val[c] = -s2g[b*2048 + c]; idx[c] = c; }
    __syncthreads();
    // bitonic ascending on val=-s2  => s2 descending
    for (int kk = 2; kk <= 2048; kk <<= 1)
        for (int jj = kk >> 1; jj > 0; jj >>= 1){
            for (int c = t; c < 2048; c += 1024){
                int ixj = c ^ jj;
                if (ixj > c){
                    bool up = ((c & kk) == 0);
                    float av = val[c], bv = val[ixj];
                    if ((av > bv) == up){
                        val[c] = bv; val[ixj] = av;
                        int ia = idx[c]; idx[c] = idx[ixj]; idx[ixj] = ia;
                    }
                }
            }
            __syncthreads();
        }
    const float M2 = -val[0];
    for (int c = t; c < 2048; c += 1024){
        float sv = -val[c] - M2;            // <= 0
        sa[c] = expf(sv);
        fa[c] = expf(0.01f * sv);
    }
    __syncthreads();
    // Hillis-Steele inclusive scans
    float *ss = sa, *sd = sb, *fs = fa, *fd = fb;
    for (int d = 1; d < 2048; d <<= 1){
        for (int c = t; c < 2048; c += 1024){
            sd[c] = ss[c] + (c >= d ? ss[c-d] : 0.f);
            fd[c] = fs[c] + (c >= d ? fs[c-d] : 0.f);
        }
        __syncthreads();
        float* tmp = ss; ss = sd; sd = tmp;
        tmp = fs; fs = fd; fd = tmp;
    }
    if (t == 0){ SEx[b*2049] = 0.f; SFx[b*2049] = 0.f; M2b[b] = M2; }
    for (int c = t; c < 2048; c += 1024){
        s2s[b*2048 + c]  = -val[c];
        perm[b*2048 + c] = idx[c];
        SEx[b*2049 + c + 1] = ss[c];
        SFx[b*2049 + c + 1] = fs[c];
        float dv = s2g[b*2048 + c] - M2;
        Eo[b*2048 + c] = expf(dv);
        Fo[b*2048 + c] = expf(0.01f * dv);
    }
}

// ---------- kernel 4: chunk-local exclusive prefix of w_c * h[perm[c]][d] ----------
__global__ __launch_bounds__(256) void k_scanA(
    const float* __restrict__ h, const int* __restrict__ perm,
    const float* __restrict__ Eo, const float* __restrict__ Fo,
    float* __restrict__ PEc, float* __restrict__ PFc,
    float* __restrict__ PEt, float* __restrict__ PFt)
{
    const int b = blockIdx.x, ch = blockIdx.y;
    const int t = threadIdx.x;
    const bool isF = t >= 128;
    const int d = t & 127;
    const float* Wv = isF ? Fo : Eo;
    float* Pc = isF ? PFc : PEc;
    float* Pt = isF ? PFt : PEt;
    float acc = 0.f;
    const int c0 = ch * 128;
    #pragma unroll 4
    for (int c = c0; c < c0 + 128; ++c){
        int j = perm[b*2048 + c];
        float w = Wv[b*2048 + j];
        float hv = h[(size_t)(b*2048 + j)*128 + d];
        Pc[(size_t)(b*2048 + c)*128 + d] = acc;
        acc += w * hv;
    }
    Pt[(b*16 + ch)*128 + d] = acc;
}

// ---------- kernel 5: chunk offsets ----------
__global__ __launch_bounds__(256) void k_scanB(
    const float* __restrict__ PEt, const float* __restrict__ PFt,
    float* __restrict__ PEo, float* __restrict__ PFo)
{
    const int b = blockIdx.x, t = threadIdx.x;
    const bool isF = t >= 128;
    const int d = t & 127;
    const float* Pt = isF ? PFt : PEt;
    float* Po = isF ? PFo : PEo;
    float acc = 0.f;
    Po[(b*17)*128 + d] = 0.f;
    for (int ch = 0; ch < 16; ++ch){
        acc += Pt[(b*16 + ch)*128 + d];
        Po[(b*17 + ch + 1)*128 + d] = acc;
    }
}

// ---------- kernel 6: attentioned -> LN2 -> ff1 -> elu -> h_next ; store A/Z,B/Z ----------
__global__ __launch_bounds__(256) void k_attn_out(
    const float* __restrict__ x, const float* __restrict__ s1g,
    const float* __restrict__ s2s, const float* __restrict__ SEx, const float* __restrict__ SFx,
    const float* __restrict__ PEc, const float* __restrict__ PFc,
    const float* __restrict__ PEo, const float* __restrict__ PFo,
    const float* __restrict__ M2b,
    const float* __restrict__ g2, const float* __restrict__ b2,
    const float* __restrict__ Wff1,
    float* __restrict__ hout, float* __restrict__ Ap, float* __restrict__ Bp,
    int addFlag)
{
    __shared__ float Wl[128*128];
    const int tid = threadIdx.x;
    stageW(Wff1, Wl, tid);
    const int wv = tid >> 6, lane = tid & 63;
    const int row = blockIdx.x * 4 + wv;
    const int b = row >> 11;
    const float s1v = s1g[row];
    const float M2 = M2b[b];
    const float t0 = s1v + M2;
    const float m  = (t0 >= 0.f) ? t0 : 0.01f*t0;      // row max of e
    const float A  = expf(t0 - m);
    const float B  = expf(0.01f*t0 - m);
    // c = #{j : s2_j >= -s1v} via binary search on descending s2s
    int lo = 0, hi = 2048;
    while (lo < hi){
        int mid = (lo + hi) >> 1;
        if (s2s[b*2048 + mid] >= -s1v) lo = mid + 1; else hi = mid;
    }
    const int c = lo;
    const float ZE  = SEx[b*2049 + c];
    const float ZF  = SFx[b*2049 + c];
    const float ZFt = SFx[b*2049 + 2048];
    const float Z = A*ZE + B*(ZFt - ZF);
    if (lane == 0){ Ap[row] = A / Z; Bp[row] = B / Z; }
    const float rz = 1.f / Z;
    const int ch = c >> 7;
    const int d0 = lane, d1 = lane + 64;
    float pe0 = PEo[(b*17 + ch)*128 + d0], pe1 = PEo[(b*17 + ch)*128 + d1];
    float pf0 = PFo[(b*17 + ch)*128 + d0], pf1 = PFo[(b*17 + ch)*128 + d1];
    if (c < 2048){
        pe0 += PEc[(size_t)(b*2048 + c)*128 + d0];
        pe1 += PEc[(size_t)(b*2048 + c)*128 + d1];
        pf0 += PFc[(size_t)(b*2048 + c)*128 + d0];
        pf1 += PFc[(size_t)(b*2048 + c)*128 + d1];
    }
    const float pft0 = PFo[(b*17 + 16)*128 + d0], pft1 = PFo[(b*17 + 16)*128 + d1];
    float a0 = (A*pe0 + B*(pft0 - pf0))*rz + x[row*128 + d0];
    float a1 = (A*pe1 + B*(pft1 - pf1))*rz + x[row*128 + d1];
    // LN2
    float mean = waveSum(a0 + a1) * (1.f/128.f);
    float c0 = a0 - mean, c1 = a1 - mean;
    float var = waveSum(c0*c0 + c1*c1) * (1.f/128.f);
    float rstd = rsqrtf(var + EPS);
    float n0 = c0*rstd*g2[d0] + b2[d0];
    float n1 = c1*rstd*g2[d1] + b2[d1];
    __syncthreads();   // Wl ready (staged above)
    float o0, o1;
    gemm128(Wl, n0, n1, lane, o0, o1);
    float u0 = (o0 > 0.f) ? o0 : expm1f(o0);
    float u1 = (o1 > 0.f) ? o1 : expm1f(o1);
    u0 *= 0.5f; u1 *= 0.5f;
    if (addFlag){
        hout[row*128 + d0] += u0; hout[row*128 + d1] += u1;
    } else {
        hout[row*128 + d0] = u0; hout[row*128 + d1] = u1;
    }
}

// ---------- kernel 7: atten_agg[b][i][j] = 0.5*(term_k0 + term_k1) ----------
__global__ __launch_bounds__(256) void k_agg(
    const float* __restrict__ s1_0, const float* __restrict__ s2_0,
    const float* __restrict__ E0, const float* __restrict__ F0,
    const float* __restrict__ Ap0, const float* __restrict__ Bp0,
    const float* __restrict__ s1_1, const float* __restrict__ s2_1,
    const float* __restrict__ E1, const float* __restrict__ F1,
    const float* __restrict__ Ap1, const float* __restrict__ Bp1,
    float* __restrict__ agg)
{
    __shared__ __align__(16) float s2a[2048], ea[2048], fa[2048];
    __shared__ __align__(16) float s2b[2048], eb[2048], fb[2048];
    const int b = blockIdx.x >> 6;
    const int tile = blockIdx.x & 63;
    const int t = threadIdx.x;
    for (int j = t; j < 2048; j += 256){
        s2a[j] = s2_0[b*2048 + j]; ea[j] = E0[b*2048 + j]; fa[j] = F0[b*2048 + j];
        s2b[j] = s2_1[b*2048 + j]; eb[j] = E1[b*2048 + j]; fb[j] = F1[b*2048 + j];
    }
    __syncthreads();
    for (int r = 0; r < 32; ++r){
        const int i = tile*32 + r;
        const int row = b*2048 + i;
        const float pa = Ap0[row], pb = Bp0[row], sa1 = s1_0[row];
        const float qa = Ap1[row], qb = Bp1[row], sb1 = s1_1[row];
        float4* outp = (float4*)(agg + (size_t)row * 2048);
        for (int j4 = t; j4 < 512; j4 += 256){
            float4 va  = ((const float4*)s2a)[j4];
            float4 vea = ((const float4*)ea )[j4];
            float4 vfa = ((const float4*)fa )[j4];
            float4 vb  = ((const float4*)s2b)[j4];
            float4 veb = ((const float4*)eb )[j4];
            float4 vfb = ((const float4*)fb )[j4];
            float4 o;
            o.x = 0.5f*(((sa1+va.x >= 0.f) ? pa*vea.x : pb*vfa.x) + ((sb1+vb.x >= 0.f) ? qa*veb.x : qb*vfb.x));
            o.y = 0.5f*(((sa1+va.y >= 0.f) ? pa*vea.y : pb*vfa.y) + ((sb1+vb.y >= 0.f) ? qa*veb.y : qb*vfb.y));
            o.z = 0.5f*(((sa1+va.z >= 0.f) ? pa*vea.z : pb*vfa.z) + ((sb1+vb.z >= 0.f) ? qa*veb.z : qb*vfb.z));
            o.w = 0.5f*(((sa1+va.w >= 0.f) ? pa*vea.w : pb*vfa.w) + ((sb1+vb.w >= 0.f) ? qa*veb.w : qb*vfb.w));
            outp[j4] = o;
        }
    }
}

// ---------- launch ----------
extern "C" void kernel_launch(void* const* d_in, const int* in_sizes, int n_in,
                              void* d_out, int out_size, void* d_ws, size_t ws_size,
                              hipStream_t stream)
{
    const float* xin  = (const float*)d_in[0];
    const float* enc  = (const float*)d_in[1];
    const float* Wenc = (const float*)d_in[2];
    const float* benc = (const float*)d_in[3];
    const float* g1   = (const float*)d_in[4];
    const float* b1   = (const float*)d_in[5];
    const float* g2   = (const float*)d_in[6];
    const float* b2   = (const float*)d_in[7];
    const float* ff0  = (const float*)d_in[8];   // [2][128][128]
    const float* ff1  = (const float*)d_in[9];   // [2][128][128]
    const float* aw   = (const float*)d_in[10];  // [2][256]

    float* out = (float*)d_out;
    float* agg = out + (size_t)ROWS * 128;

    const size_t R = ROWS, RD = (size_t)ROWS * 128;
    float* ws  = (float*)d_ws;
    float* x   = ws;
    float* xn  = x + RD;
    float* h   = xn + RD;
    float* PEc = h + RD;
    float* PFc = PEc + RD;
    float* PEt = PFc + RD;       // 8*16*128
    float* PFt = PEt + 16384;
    float* PEo = PFt + 16384;    // 8*17*128
    float* PFo = PEo + 17408;
    float* s2s = PFo + 17408;    // 8*2048
    int*   perm = (int*)(s2s + 16384);
    float* SEx = (float*)(perm + 16384); // 8*2049
    float* SFx = SEx + 16392;
    float* M2b = SFx + 16392;    // 8
    float* s1k = M2b + 8;        // [2][ROWS]
    float* s2k = s1k + 2*R;
    float* Ek  = s2k + 2*R;
    float* Fk  = Ek + 2*R;
    float* Apk = Fk + 2*R;
    float* Bpk = Apk + 2*R;

    k_enc_ln1<<<ROWS/4, 256, 0, stream>>>(xin, enc, Wenc, benc, g1, b1, x, xn);

    for (int k = 0; k < 2; ++k){
        k_h<<<ROWS/4, 256, 0, stream>>>(xn, ff0 + (size_t)k*128*128, aw + k*256,
                                        h, s1k + k*R, s2k + k*R);
        k_sort<<<BSZ, 1024, 0, stream>>>(s2k + k*R, s2s, perm, SEx, SFx,
                                         Ek + k*R, Fk + k*R, M2b);
        k_scanA<<<dim3(BSZ, 16), 256, 0, stream>>>(h, perm, Ek + k*R, Fk + k*R,
                                                   PEc, PFc, PEt, PFt);
        k_scanB<<<BSZ, 256, 0, stream>>>(PEt, PFt, PEo, PFo);
        k_attn_out<<<ROWS/4, 256, 0, stream>>>(x, s1k + k*R, s2s, SEx, SFx,
                                               PEc, PFc, PEo, PFo, M2b,
                                               g2, b2, ff1 + (size_t)k*128*128,
                                               out, Apk + k*R, Bpk + k*R, k);
    }

    k_agg<<<BSZ*64, 256, 0, stream>>>(s1k, s2k, Ek, Fk, Apk, Bpk,
                                      s1k + R, s2k + R, Ek + R, Fk + R, Apk + R, Bpk + R,
                                      agg);
}

// Round 9
// 388.202 us; speedup vs baseline: 2.5384x; 2.5384x over previous
//
#include <hip/hip_runtime.h>
#include <hip/hip_bf16.h>
#include <math.h>

#define BSZ 8
#define NSEQ 2048
#define DD 128
#define ROWS (BSZ*NSEQ)
#define EPS 1e-5f

__device__ __forceinline__ float f4get(const float4& v, int i){
    return i==0 ? v.x : i==1 ? v.y : i==2 ? v.z : v.w;
}
__device__ __forceinline__ float eluf(float z){ return z > 0.f ? z : expm1f(z); }

// ---------- weight pre-transpose: Wt[m][i][o] = W[m][o][i] ----------
__global__ __launch_bounds__(256) void k_transpose(
    const float* __restrict__ Wenc, const float* __restrict__ ff0,
    const float* __restrict__ ff1, float* __restrict__ Wt)
{
    __shared__ float t[32][33];
    const int m = blockIdx.x >> 4;
    const int tile = blockIdx.x & 15;
    const int ti = tile >> 2, tj = tile & 3;
    const float* src = (m == 0) ? Wenc
                     : (m <= 2) ? ff0 + (size_t)(m-1)*16384
                                : ff1 + (size_t)(m-3)*16384;
    float* dst = Wt + (size_t)m*16384;
    const int c = threadIdx.x & 31, r8 = threadIdx.x >> 5;
    #pragma unroll
    for (int p = 0; p < 4; ++p){
        int r = r8 + p*8;
        t[r][c] = src[(ti*32 + r)*128 + tj*32 + c];
    }
    __syncthreads();
    #pragma unroll
    for (int p = 0; p < 4; ++p){
        int r = r8 + p*8;
        dst[(tj*32 + r)*128 + ti*32 + c] = t[c][r];
    }
}

// ---------- tiled fp32 GEMM: C[r][o] = sum_d A[r][d]*Bt[d][o], fused epilogues ----------
// MODE 0 (ENC):  v = acc + P0(xin) + P1(benc); C=x; LN(g=P2,b=P3) -> O1(xn)
// MODE 1 (H):    C=h; s1=acc.P1[0:128] -> O1; s2=acc.P1[128:256] -> O2
// MODE 4 (Honly):     s1/s2 only, no C store
// MODE 2 (RAW):  C = acc
// MODE 5 (FF1A): C = 0.5*elu(acc)            (overwrite)
// MODE 3 (FF1B): C += 0.5*elu(acc)           (read-modify-write)
template<int MODE>
__global__ __launch_bounds__(256) void k_gemm(
    const float* __restrict__ A, const float* __restrict__ Bt,
    float* __restrict__ C,
    const float* __restrict__ P0, const float* __restrict__ P1,
    const float* __restrict__ P2, const float* __restrict__ P3,
    float* __restrict__ O1, float* __restrict__ O2)
{
    __shared__ float As[64][36];
    __shared__ float Bs[32][128];
    const int tid = threadIdx.x;
    const int tx = tid & 15, ty = tid >> 4;
    const int rowBase = blockIdx.x * 64;

    float acc[4][8];
    #pragma unroll
    for (int i = 0; i < 4; ++i)
        #pragma unroll
        for (int j = 0; j < 8; ++j) acc[i][j] = 0.f;

    for (int k0 = 0; k0 < 128; k0 += 32){
        {   // stage A slab 64x32
            const int kk = tid & 31, rr = tid >> 5;
            #pragma unroll
            for (int p = 0; p < 8; ++p){
                int r = rr + p*8;
                As[r][kk] = A[(size_t)(rowBase + r)*128 + k0 + kk];
            }
        }
        {   // stage B slab 32x128
            const int n = tid & 127, kk2 = tid >> 7;
            #pragma unroll
            for (int p = 0; p < 16; ++p){
                int kk = kk2 + p*2;
                Bs[kk][n] = Bt[(size_t)(k0 + kk)*128 + n];
            }
        }
        __syncthreads();
        #pragma unroll
        for (int kk4 = 0; kk4 < 32; kk4 += 4){
            float4 a[4];
            float4 b[4][2];
            #pragma unroll
            for (int rr = 0; rr < 4; ++rr)
                a[rr] = *(const float4*)&As[4*ty + rr][kk4];
            #pragma unroll
            for (int kk = 0; kk < 4; ++kk){
                b[kk][0] = *(const float4*)&Bs[kk4 + kk][8*tx];
                b[kk][1] = *(const float4*)&Bs[kk4 + kk][8*tx + 4];
            }
            #pragma unroll
            for (int kk = 0; kk < 4; ++kk){
                float bb[8] = {b[kk][0].x, b[kk][0].y, b[kk][0].z, b[kk][0].w,
                               b[kk][1].x, b[kk][1].y, b[kk][1].z, b[kk][1].w};
                #pragma unroll
                for (int rr = 0; rr < 4; ++rr){
                    float av = f4get(a[rr], kk);
                    #pragma unroll
                    for (int cc = 0; cc < 8; ++cc)
                        acc[rr][cc] += av * bb[cc];
                }
            }
        }
        __syncthreads();
    }

    const int c0 = 8*tx;
    if (MODE == 0){
        float4 be0 = *(const float4*)&P1[c0], be1 = *(const float4*)&P1[c0+4];
        float4 g0  = *(const float4*)&P2[c0], g1v = *(const float4*)&P2[c0+4];
        float4 bb0 = *(const float4*)&P3[c0], bb1 = *(const float4*)&P3[c0+4];
        #pragma unroll
        for (int rr = 0; rr < 4; ++rr){
            const size_t off = (size_t)(rowBase + 4*ty + rr)*128 + c0;
            float4 xi0 = *(const float4*)&P0[off];
            float4 xi1 = *(const float4*)&P0[off+4];
            float v[8];
            v[0]=acc[rr][0]+xi0.x+be0.x; v[1]=acc[rr][1]+xi0.y+be0.y;
            v[2]=acc[rr][2]+xi0.z+be0.z; v[3]=acc[rr][3]+xi0.w+be0.w;
            v[4]=acc[rr][4]+xi1.x+be1.x; v[5]=acc[rr][5]+xi1.y+be1.y;
            v[6]=acc[rr][6]+xi1.z+be1.z; v[7]=acc[rr][7]+xi1.w+be1.w;
            *(float4*)&C[off]   = make_float4(v[0],v[1],v[2],v[3]);
            *(float4*)&C[off+4] = make_float4(v[4],v[5],v[6],v[7]);
            float s = v[0]+v[1]+v[2]+v[3]+v[4]+v[5]+v[6]+v[7];
            #pragma unroll
            for (int m = 1; m < 16; m <<= 1) s += __shfl_xor(s, m, 64);
            float mean = s * (1.f/128.f);
            float q = 0.f;
            #pragma unroll
            for (int j = 0; j < 8; ++j){ float d = v[j]-mean; q += d*d; }
            #pragma unroll
            for (int m = 1; m < 16; m <<= 1) q += __shfl_xor(q, m, 64);
            float rstd = rsqrtf(q * (1.f/128.f) + EPS);
            float o[8];
            o[0]=(v[0]-mean)*rstd*g0.x+bb0.x; o[1]=(v[1]-mean)*rstd*g0.y+bb0.y;
            o[2]=(v[2]-mean)*rstd*g0.z+bb0.z; o[3]=(v[3]-mean)*rstd*g0.w+bb0.w;
            o[4]=(v[4]-mean)*rstd*g1v.x+bb1.x; o[5]=(v[5]-mean)*rstd*g1v.y+bb1.y;
            o[6]=(v[6]-mean)*rstd*g1v.z+bb1.z; o[7]=(v[7]-mean)*rstd*g1v.w+bb1.w;
            *(float4*)&O1[off]   = make_float4(o[0],o[1],o[2],o[3]);
            *(float4*)&O1[off+4] = make_float4(o[4],o[5],o[6],o[7]);
        }
    } else if (MODE == 1 || MODE == 4){
        float4 a10 = *(const float4*)&P1[c0],     a11 = *(const float4*)&P1[c0+4];
        float4 a20 = *(const float4*)&P1[128+c0], a21 = *(const float4*)&P1[128+c0+4];
        #pragma unroll
        for (int rr = 0; rr < 4; ++rr){
            const size_t off = (size_t)(rowBase + 4*ty + rr)*128 + c0;
            if (MODE == 1){
                *(float4*)&C[off]   = make_float4(acc[rr][0],acc[rr][1],acc[rr][2],acc[rr][3]);
                *(float4*)&C[off+4] = make_float4(acc[rr][4],acc[rr][5],acc[rr][6],acc[rr][7]);
            }
            float p1 = acc[rr][0]*a10.x+acc[rr][1]*a10.y+acc[rr][2]*a10.z+acc[rr][3]*a10.w
                     + acc[rr][4]*a11.x+acc[rr][5]*a11.y+acc[rr][6]*a11.z+acc[rr][7]*a11.w;
            float p2 = acc[rr][0]*a20.x+acc[rr][1]*a20.y+acc[rr][2]*a20.z+acc[rr][3]*a20.w
                     + acc[rr][4]*a21.x+acc[rr][5]*a21.y+acc[rr][6]*a21.z+acc[rr][7]*a21.w;
            #pragma unroll
            for (int m = 1; m < 16; m <<= 1){
                p1 += __shfl_xor(p1, m, 64);
                p2 += __shfl_xor(p2, m, 64);
            }
            if (tx == 0){
                O1[rowBase + 4*ty + rr] = p1;
                O2[rowBase + 4*ty + rr] = p2;
            }
        }
    } else if (MODE == 2){
        #pragma unroll
        for (int rr = 0; rr < 4; ++rr){
            const size_t off = (size_t)(rowBase + 4*ty + rr)*128 + c0;
            *(float4*)&C[off]   = make_float4(acc[rr][0],acc[rr][1],acc[rr][2],acc[rr][3]);
            *(float4*)&C[off+4] = make_float4(acc[rr][4],acc[rr][5],acc[rr][6],acc[rr][7]);
        }
    } else { // MODE 5 (overwrite) / MODE 3 (accumulate)
        #pragma unroll
        for (int rr = 0; rr < 4; ++rr){
            const size_t off = (size_t)(rowBase + 4*ty + rr)*128 + c0;
            float u[8];
            #pragma unroll
            for (int j = 0; j < 8; ++j) u[j] = 0.5f*eluf(acc[rr][j]);
            if (MODE == 3){
                float4 pa = *(const float4*)&C[off];
                float4 pb = *(const float4*)&C[off+4];
                u[0]+=pa.x; u[1]+=pa.y; u[2]+=pa.z; u[3]+=pa.w;
                u[4]+=pb.x; u[5]+=pb.y; u[6]+=pb.z; u[7]+=pb.w;
            }
            *(float4*)&C[off]   = make_float4(u[0],u[1],u[2],u[3]);
            *(float4*)&C[off+4] = make_float4(u[4],u[5],u[6],u[7]);
        }
    }
}

// ---------- sort (both k): per-(k,b) bitonic + scalar prefix scans + E/F ----------
__global__ __launch_bounds__(1024) void k_sort(
    const float* __restrict__ s2k,
    float* __restrict__ s2s, int* __restrict__ perm,
    float* __restrict__ SEx, float* __restrict__ SFx,
    float* __restrict__ Eo, float* __restrict__ Fo,
    float* __restrict__ M2b)
{
    __shared__ float val[2048];
    __shared__ int   idx[2048];
    __shared__ float sa[2048], sb[2048], fa[2048], fb[2048];
    const int k = blockIdx.x >> 3, b = blockIdx.x & 7;
    const int t = threadIdx.x;
    const float* s2g = s2k + (size_t)k*ROWS + b*2048;
    float* s2so = s2s + k*16384 + b*2048;
    int*   permo = perm + k*16384 + b*2048;
    float* SExo = SEx + k*16392 + b*2049;
    float* SFxo = SFx + k*16392 + b*2049;
    float* Eok = Eo + (size_t)k*ROWS + b*2048;
    float* Fok = Fo + (size_t)k*ROWS + b*2048;

    for (int c = t; c < 2048; c += 1024){ val[c] = -s2g[c]; idx[c] = c; }
    __syncthreads();
    for (int kk = 2; kk <= 2048; kk <<= 1)
        for (int jj = kk >> 1; jj > 0; jj >>= 1){
            for (int c = t; c < 2048; c += 1024){
                int ixj = c ^ jj;
                if (ixj > c){
                    bool up = ((c & kk) == 0);
                    float av = val[c], bv = val[ixj];
                    if ((av > bv) == up){
                        val[c] = bv; val[ixj] = av;
                        int ia = idx[c]; idx[c] = idx[ixj]; idx[ixj] = ia;
                    }
                }
            }
            __syncthreads();
        }
    const float M2 = -val[0];
    for (int c = t; c < 2048; c += 1024){
        float sv = -val[c] - M2;
        sa[c] = expf(sv);
        fa[c] = expf(0.01f * sv);
    }
    __syncthreads();
    float *ss = sa, *sd = sb, *fs = fa, *fd = fb;
    for (int d = 1; d < 2048; d <<= 1){
        for (int c = t; c < 2048; c += 1024){
            sd[c] = ss[c] + (c >= d ? ss[c-d] : 0.f);
            fd[c] = fs[c] + (c >= d ? fs[c-d] : 0.f);
        }
        __syncthreads();
        float* tmp = ss; ss = sd; sd = tmp;
        tmp = fs; fs = fd; fd = tmp;
    }
    if (t == 0){ SExo[0] = 0.f; SFxo[0] = 0.f; M2b[k*8 + b] = M2; }
    for (int c = t; c < 2048; c += 1024){
        s2so[c]  = -val[c];
        permo[c] = idx[c];
        SExo[c + 1] = ss[c];
        SFxo[c + 1] = fs[c];
        float dv = s2g[c] - M2;
        Eok[c] = expf(dv);
        Fok[c] = expf(0.01f * dv);
    }
}

// ---------- chunk-local exclusive prefix ----------
__global__ __launch_bounds__(256) void k_scanA(
    const float* __restrict__ h, const int* __restrict__ perm,
    const float* __restrict__ Eo, const float* __restrict__ Fo,
    float* __restrict__ PEc, float* __restrict__ PFc,
    float* __restrict__ PEt, float* __restrict__ PFt)
{
    const int b = blockIdx.x, ch = blockIdx.y;
    const int t = threadIdx.x;
    const bool isF = t >= 128;
    const int d = t & 127;
    const float* Wv = isF ? Fo : Eo;
    float* Pc = isF ? PFc : PEc;
    float* Pt = isF ? PFt : PEt;
    float acc = 0.f;
    const int c0 = ch * 128;
    #pragma unroll 4
    for (int c = c0; c < c0 + 128; ++c){
        int j = perm[b*2048 + c];
        float w = Wv[b*2048 + j];
        float hv = h[(size_t)(b*2048 + j)*128 + d];
        Pc[(size_t)(b*2048 + c)*128 + d] = acc;
        acc += w * hv;
    }
    Pt[(b*16 + ch)*128 + d] = acc;
}

// ---------- chunk offsets ----------
__global__ __launch_bounds__(256) void k_scanB(
    const float* __restrict__ PEt, const float* __restrict__ PFt,
    float* __restrict__ PEo, float* __restrict__ PFo)
{
    const int b = blockIdx.x, t = threadIdx.x;
    const bool isF = t >= 128;
    const int d = t & 127;
    const float* Pt = isF ? PFt : PEt;
    float* Po = isF ? PFo : PEo;
    float acc = 0.f;
    Po[(b*17)*128 + d] = 0.f;
    for (int ch = 0; ch < 16; ++ch){
        acc += Pt[(b*16 + ch)*128 + d];
        Po[(b*17 + ch + 1)*128 + d] = acc;
    }
}

// ---------- attn pre: attentioned -> LN2 -> n ; store A/Z, B/Z ----------
__global__ __launch_bounds__(256) void k_attn_pre(
    const float* __restrict__ x, const float* __restrict__ s1g,
    const float* __restrict__ s2s, const float* __restrict__ SEx, const float* __restrict__ SFx,
    const float* __restrict__ PEc, const float* __restrict__ PFc,
    const float* __restrict__ PEo, const float* __restrict__ PFo,
    const float* __restrict__ M2b,
    const float* __restrict__ g2, const float* __restrict__ b2,
    float* __restrict__ nout, float* __restrict__ Ap, float* __restrict__ Bp)
{
    const int tid = threadIdx.x;
    const int wv = tid >> 6, lane = tid & 63;
    const int row = blockIdx.x * 4 + wv;
    const int b = row >> 11;
    const float s1v = s1g[row];
    const float M2 = M2b[b];
    const float t0 = s1v + M2;
    const float m  = (t0 >= 0.f) ? t0 : 0.01f*t0;
    const float A  = expf(t0 - m);
    const float B  = expf(0.01f*t0 - m);
    int lo = 0, hi = 2048;
    while (lo < hi){
        int mid = (lo + hi) >> 1;
        if (s2s[b*2048 + mid] >= -s1v) lo = mid + 1; else hi = mid;
    }
    const int c = lo;
    const float ZE  = SEx[b*2049 + c];
    const float ZF  = SFx[b*2049 + c];
    const float ZFt = SFx[b*2049 + 2048];
    const float Z = A*ZE + B*(ZFt - ZF);
    if (lane == 0){ Ap[row] = A / Z; Bp[row] = B / Z; }
    const float rz = 1.f / Z;
    const int ch = c >> 7;
    const int d0 = lane, d1 = lane + 64;
    float pe0 = PEo[(b*17 + ch)*128 + d0], pe1 = PEo[(b*17 + ch)*128 + d1];
    float pf0 = PFo[(b*17 + ch)*128 + d0], pf1 = PFo[(b*17 + ch)*128 + d1];
    if (c < 2048){
        pe0 += PEc[(size_t)(b*2048 + c)*128 + d0];
        pe1 += PEc[(size_t)(b*2048 + c)*128 + d1];
        pf0 += PFc[(size_t)(b*2048 + c)*128 + d0];
        pf1 += PFc[(size_t)(b*2048 + c)*128 + d1];
    }
    const float pft0 = PFo[(b*17 + 16)*128 + d0], pft1 = PFo[(b*17 + 16)*128 + d1];
    float a0 = (A*pe0 + B*(pft0 - pf0))*rz + x[row*128 + d0];
    float a1 = (A*pe1 + B*(pft1 - pf1))*rz + x[row*128 + d1];
    float s = a0 + a1;
    #pragma unroll
    for (int mm = 32; mm; mm >>= 1) s += __shfl_xor(s, mm, 64);
    float mean = s * (1.f/128.f);
    float c0v = a0 - mean, c1v = a1 - mean;
    float q = c0v*c0v + c1v*c1v;
    #pragma unroll
    for (int mm = 32; mm; mm >>= 1) q += __shfl_xor(q, mm, 64);
    float rstd = rsqrtf(q * (1.f/128.f) + EPS);
    nout[row*128 + d0] = c0v*rstd*g2[d0] + b2[d0];
    nout[row*128 + d1] = c1v*rstd*g2[d1] + b2[d1];
}

// ---------- agg ----------
__global__ __launch_bounds__(256) void k_agg(
    const float* __restrict__ s1_0, const float* __restrict__ s2_0,
    const float* __restrict__ E0, const float* __restrict__ F0,
    const float* __restrict__ Ap0, const float* __restrict__ Bp0,
    const float* __restrict__ s1_1, const float* __restrict__ s2_1,
    const float* __restrict__ E1, const float* __restrict__ F1,
    const float* __restrict__ Ap1, const float* __restrict__ Bp1,
    float* __restrict__ agg)
{
    __shared__ __align__(16) float s2a[2048], ea[2048], fa[2048];
    __shared__ __align__(16) float s2b[2048], eb[2048], fb[2048];
    const int b = blockIdx.x >> 6;
    const int tile = blockIdx.x & 63;
    const int t = threadIdx.x;
    for (int j = t; j < 2048; j += 256){
        s2a[j] = s2_0[b*2048 + j]; ea[j] = E0[b*2048 + j]; fa[j] = F0[b*2048 + j];
        s2b[j] = s2_1[b*2048 + j]; eb[j] = E1[b*2048 + j]; fb[j] = F1[b*2048 + j];
    }
    __syncthreads();
    for (int r = 0; r < 32; ++r){
        const int i = tile*32 + r;
        const int row = b*2048 + i;
        const float pa = Ap0[row], pb = Bp0[row], sa1 = s1_0[row];
        const float qa = Ap1[row], qb = Bp1[row], sb1 = s1_1[row];
        float4* outp = (float4*)(agg + (size_t)row * 2048);
        for (int j4 = t; j4 < 512; j4 += 256){
            float4 va  = ((const float4*)s2a)[j4];
            float4 vea = ((const float4*)ea )[j4];
            float4 vfa = ((const float4*)fa )[j4];
            float4 vb  = ((const float4*)s2b)[j4];
            float4 veb = ((const float4*)eb )[j4];
            float4 vfb = ((const float4*)fb )[j4];
            float4 o;
            o.x = 0.5f*(((sa1+va.x >= 0.f) ? pa*vea.x : pb*vfa.x) + ((sb1+vb.x >= 0.f) ? qa*veb.x : qb*vfb.x));
            o.y = 0.5f*(((sa1+va.y >= 0.f) ? pa*vea.y : pb*vfa.y) + ((sb1+vb.y >= 0.f) ? qa*veb.y : qb*vfb.y));
            o.z = 0.5f*(((sa1+va.z >= 0.f) ? pa*vea.z : pb*vfa.z) + ((sb1+vb.z >= 0.f) ? qa*veb.z : qb*vfb.z));
            o.w = 0.5f*(((sa1+va.w >= 0.f) ? pa*vea.w : pb*vfa.w) + ((sb1+vb.w >= 0.f) ? qa*veb.w : qb*vfb.w));
            outp[j4] = o;
        }
    }
}

// ---------- launch ----------
extern "C" void kernel_launch(void* const* d_in, const int* in_sizes, int n_in,
                              void* d_out, int out_size, void* d_ws, size_t ws_size,
                              hipStream_t stream)
{
    const float* xin  = (const float*)d_in[0];
    const float* enc  = (const float*)d_in[1];
    const float* Wenc = (const float*)d_in[2];
    const float* benc = (const float*)d_in[3];
    const float* g1   = (const float*)d_in[4];
    const float* b1   = (const float*)d_in[5];
    const float* g2   = (const float*)d_in[6];
    const float* b2   = (const float*)d_in[7];
    const float* ff0  = (const float*)d_in[8];
    const float* ff1  = (const float*)d_in[9];
    const float* aw   = (const float*)d_in[10];

    float* out = (float*)d_out;
    float* agg = out + (size_t)ROWS * 128;

    const size_t R = ROWS, RD = (size_t)ROWS * 128;
    float* ws  = (float*)d_ws;
    float* Wt  = ws;                 // 5*16384
    float* x   = Wt + 5*16384;       // RD
    float* xn  = x + RD;             // RD
    float* h   = xn + RD;            // RD (doubles as LN2-output buffer)
    float* PEc = h + RD;             // RD
    float* PFc = PEc + RD;           // RD
    float* PEt = PFc + RD;           // 8*16*128
    float* PFt = PEt + 16384;
    float* PEo = PFt + 16384;        // 8*17*128
    float* PFo = PEo + 17408;
    float* s2s = PFo + 17408;        // 2*8*2048
    int*   perm = (int*)(s2s + 2*16384);
    float* SEx = (float*)(perm + 2*16384);  // 2*8*2049
    float* SFx = SEx + 2*16392;
    float* M2b = SFx + 2*16392;      // 16
    float* s1k = M2b + 16;           // [2][R]
    float* s2k = s1k + 2*R;
    float* Ek  = s2k + 2*R;
    float* Fk  = Ek + 2*R;
    float* Apk = Fk + 2*R;
    float* Bpk = Apk + 2*R;
    // total: 10,962,992 floats = 41.8 MiB  (round-1's proven envelope was 41.3)

    k_transpose<<<80, 256, 0, stream>>>(Wenc, ff0, ff1, Wt);

    k_gemm<0><<<ROWS/64, 256, 0, stream>>>(enc, Wt, x, xin, benc, g1, b1, xn, nullptr);

    // k=0: h + s1/s2 ; k=1: s1/s2 only (h recomputed later)
    k_gemm<1><<<ROWS/64, 256, 0, stream>>>(xn, Wt + 16384, h, nullptr, aw, nullptr, nullptr,
                                           s1k, s2k);
    k_gemm<4><<<ROWS/64, 256, 0, stream>>>(xn, Wt + 2*16384, nullptr, nullptr, aw + 256,
                                           nullptr, nullptr, s1k + R, s2k + R);

    k_sort<<<16, 1024, 0, stream>>>(s2k, s2s, perm, SEx, SFx, Ek, Fk, M2b);

    for (int k = 0; k < 2; ++k){
        if (k == 1)  // recompute h1 into shared h buffer
            k_gemm<2><<<ROWS/64, 256, 0, stream>>>(xn, Wt + 2*16384, h,
                                                   nullptr, nullptr, nullptr, nullptr,
                                                   nullptr, nullptr);
        k_scanA<<<dim3(BSZ, 16), 256, 0, stream>>>(h, perm + k*16384,
                                                   Ek + k*R, Fk + k*R,
                                                   PEc, PFc, PEt, PFt);
        k_scanB<<<BSZ, 256, 0, stream>>>(PEt, PFt, PEo, PFo);
        // LN2 output written into h (h's old contents are dead by now)
        k_attn_pre<<<ROWS/4, 256, 0, stream>>>(x, s1k + k*R, s2s + k*16384,
                                               SEx + k*16392, SFx + k*16392,
                                               PEc, PFc, PEo, PFo, M2b + k*8,
                                               g2, b2, h, Apk + k*R, Bpk + k*R);
        if (k == 0)
            k_gemm<5><<<ROWS/64, 256, 0, stream>>>(h, Wt + 3*16384, out,
                                                   nullptr, nullptr, nullptr, nullptr,
                                                   nullptr, nullptr);
        else
            k_gemm<3><<<ROWS/64, 256, 0, stream>>>(h, Wt + 4*16384, out,
                                                   nullptr, nullptr, nullptr, nullptr,
                                                   nullptr, nullptr);
    }

    k_agg<<<BSZ*64, 256, 0, stream>>>(s1k, s2k, Ek, Fk, Apk, Bpk,
                                      s1k + R, s2k + R, Ek + R, Fk + R, Apk + R, Bpk + R,
                                      agg);
}

// Round 10
// 366.443 us; speedup vs baseline: 2.6891x; 1.0594x over previous
//
#include <hip/hip_runtime.h>
#include <hip/hip_bf16.h>
#include <math.h>

#define BSZ 8
#define NSEQ 2048
#define DD 128
#define ROWS (BSZ*NSEQ)
#define EPS 1e-5f
#define CH 32
#define NCH 64

__device__ __forceinline__ float f4get(const float4& v, int i){
    return i==0 ? v.x : i==1 ? v.y : i==2 ? v.z : v.w;
}
__device__ __forceinline__ float eluf(float z){ return z > 0.f ? z : expm1f(z); }

// ---------- weight pre-transpose: Wt[m][i][o] = W[m][o][i] ----------
__global__ __launch_bounds__(256) void k_transpose(
    const float* __restrict__ Wenc, const float* __restrict__ ff0,
    const float* __restrict__ ff1, float* __restrict__ Wt)
{
    __shared__ float t[32][33];
    const int m = blockIdx.x >> 4;
    const int tile = blockIdx.x & 15;
    const int ti = tile >> 2, tj = tile & 3;
    const float* src = (m == 0) ? Wenc
                     : (m <= 2) ? ff0 + (size_t)(m-1)*16384
                                : ff1 + (size_t)(m-3)*16384;
    float* dst = Wt + (size_t)m*16384;
    const int c = threadIdx.x & 31, r8 = threadIdx.x >> 5;
    #pragma unroll
    for (int p = 0; p < 4; ++p){
        int r = r8 + p*8;
        t[r][c] = src[(ti*32 + r)*128 + tj*32 + c];
    }
    __syncthreads();
    #pragma unroll
    for (int p = 0; p < 4; ++p){
        int r = r8 + p*8;
        dst[(tj*32 + r)*128 + ti*32 + c] = t[c][r];
    }
}

// ---------- tiled fp32 GEMM (BM=32, 512+ blocks): C[r][o] = sum_d A[r][d]*Bt[d][o] ----------
// MODE 0 (ENC):  v = acc + P0(xin) + P1(benc); C=x; LN(g=P2,b=P3) -> O1(xn)
// MODE 6 (H, grid.y=2): ky=blockIdx.y selects weight/aw/outputs; C=h written only ky==0
// MODE 2 (RAW):  C = acc
// MODE 5 (FF1A): C = 0.5*elu(acc)            (overwrite)
// MODE 3 (FF1B): C += 0.5*elu(acc)           (read-modify-write)
template<int MODE>
__global__ __launch_bounds__(256) void k_gemm(
    const float* __restrict__ A, const float* __restrict__ Bt,
    float* __restrict__ C,
    const float* __restrict__ P0, const float* __restrict__ P1,
    const float* __restrict__ P2, const float* __restrict__ P3,
    float* __restrict__ O1, float* __restrict__ O2)
{
    __shared__ float As[32][36];
    __shared__ float Bs[32][128];
    const int tid = threadIdx.x;
    const int tx = tid & 15, ty = tid >> 4;      // ty 0..15, 2 rows each
    const int rowBase = blockIdx.x * 32;
    const int ky = (MODE == 6) ? blockIdx.y : 0;
    const float* Btk = Bt + (size_t)ky * 16384;

    float acc[2][8];
    #pragma unroll
    for (int i = 0; i < 2; ++i)
        #pragma unroll
        for (int j = 0; j < 8; ++j) acc[i][j] = 0.f;

    for (int k0 = 0; k0 < 128; k0 += 32){
        {   // stage A slab 32x32
            const int kk = tid & 31, rr = tid >> 5;
            #pragma unroll
            for (int p = 0; p < 4; ++p){
                int r = rr + p*8;
                As[r][kk] = A[(size_t)(rowBase + r)*128 + k0 + kk];
            }
        }
        {   // stage B slab 32x128
            const int n = tid & 127, kk2 = tid >> 7;
            #pragma unroll
            for (int p = 0; p < 16; ++p){
                int kk = kk2 + p*2;
                Bs[kk][n] = Btk[(size_t)(k0 + kk)*128 + n];
            }
        }
        __syncthreads();
        #pragma unroll
        for (int kk4 = 0; kk4 < 32; kk4 += 4){
            float4 a0 = *(const float4*)&As[2*ty    ][kk4];
            float4 a1 = *(const float4*)&As[2*ty + 1][kk4];
            float4 b[4][2];
            #pragma unroll
            for (int kk = 0; kk < 4; ++kk){
                b[kk][0] = *(const float4*)&Bs[kk4 + kk][8*tx];
                b[kk][1] = *(const float4*)&Bs[kk4 + kk][8*tx + 4];
            }
            #pragma unroll
            for (int kk = 0; kk < 4; ++kk){
                float bb[8] = {b[kk][0].x, b[kk][0].y, b[kk][0].z, b[kk][0].w,
                               b[kk][1].x, b[kk][1].y, b[kk][1].z, b[kk][1].w};
                float av0 = f4get(a0, kk), av1 = f4get(a1, kk);
                #pragma unroll
                for (int cc = 0; cc < 8; ++cc){
                    acc[0][cc] += av0 * bb[cc];
                    acc[1][cc] += av1 * bb[cc];
                }
            }
        }
        __syncthreads();
    }

    const int c0 = 8*tx;
    if (MODE == 0){
        float4 be0 = *(const float4*)&P1[c0], be1 = *(const float4*)&P1[c0+4];
        float4 g0  = *(const float4*)&P2[c0], g1v = *(const float4*)&P2[c0+4];
        float4 bb0 = *(const float4*)&P3[c0], bb1 = *(const float4*)&P3[c0+4];
        #pragma unroll
        for (int rr = 0; rr < 2; ++rr){
            const size_t off = (size_t)(rowBase + 2*ty + rr)*128 + c0;
            float4 xi0 = *(const float4*)&P0[off];
            float4 xi1 = *(const float4*)&P0[off+4];
            float v[8];
            v[0]=acc[rr][0]+xi0.x+be0.x; v[1]=acc[rr][1]+xi0.y+be0.y;
            v[2]=acc[rr][2]+xi0.z+be0.z; v[3]=acc[rr][3]+xi0.w+be0.w;
            v[4]=acc[rr][4]+xi1.x+be1.x; v[5]=acc[rr][5]+xi1.y+be1.y;
            v[6]=acc[rr][6]+xi1.z+be1.z; v[7]=acc[rr][7]+xi1.w+be1.w;
            *(float4*)&C[off]   = make_float4(v[0],v[1],v[2],v[3]);
            *(float4*)&C[off+4] = make_float4(v[4],v[5],v[6],v[7]);
            float s = v[0]+v[1]+v[2]+v[3]+v[4]+v[5]+v[6]+v[7];
            #pragma unroll
            for (int m = 1; m < 16; m <<= 1) s += __shfl_xor(s, m, 64);
            float mean = s * (1.f/128.f);
            float q = 0.f;
            #pragma unroll
            for (int j = 0; j < 8; ++j){ float dd = v[j]-mean; q += dd*dd; }
            #pragma unroll
            for (int m = 1; m < 16; m <<= 1) q += __shfl_xor(q, m, 64);
            float rstd = rsqrtf(q * (1.f/128.f) + EPS);
            float o[8];
            o[0]=(v[0]-mean)*rstd*g0.x+bb0.x; o[1]=(v[1]-mean)*rstd*g0.y+bb0.y;
            o[2]=(v[2]-mean)*rstd*g0.z+bb0.z; o[3]=(v[3]-mean)*rstd*g0.w+bb0.w;
            o[4]=(v[4]-mean)*rstd*g1v.x+bb1.x; o[5]=(v[5]-mean)*rstd*g1v.y+bb1.y;
            o[6]=(v[6]-mean)*rstd*g1v.z+bb1.z; o[7]=(v[7]-mean)*rstd*g1v.w+bb1.w;
            *(float4*)&O1[off]   = make_float4(o[0],o[1],o[2],o[3]);
            *(float4*)&O1[off+4] = make_float4(o[4],o[5],o[6],o[7]);
        }
    } else if (MODE == 6){
        const float* P1k = P1 + ky*256;
        float* O1k = O1 + (size_t)ky*ROWS;
        float* O2k = O2 + (size_t)ky*ROWS;
        float4 a10 = *(const float4*)&P1k[c0],     a11 = *(const float4*)&P1k[c0+4];
        float4 a20 = *(const float4*)&P1k[128+c0], a21 = *(const float4*)&P1k[128+c0+4];
        #pragma unroll
        for (int rr = 0; rr < 2; ++rr){
            const size_t off = (size_t)(rowBase + 2*ty + rr)*128 + c0;
            if (ky == 0){
                *(float4*)&C[off]   = make_float4(acc[rr][0],acc[rr][1],acc[rr][2],acc[rr][3]);
                *(float4*)&C[off+4] = make_float4(acc[rr][4],acc[rr][5],acc[rr][6],acc[rr][7]);
            }
            float p1 = acc[rr][0]*a10.x+acc[rr][1]*a10.y+acc[rr][2]*a10.z+acc[rr][3]*a10.w
                     + acc[rr][4]*a11.x+acc[rr][5]*a11.y+acc[rr][6]*a11.z+acc[rr][7]*a11.w;
            float p2 = acc[rr][0]*a20.x+acc[rr][1]*a20.y+acc[rr][2]*a20.z+acc[rr][3]*a20.w
                     + acc[rr][4]*a21.x+acc[rr][5]*a21.y+acc[rr][6]*a21.z+acc[rr][7]*a21.w;
            #pragma unroll
            for (int m = 1; m < 16; m <<= 1){
                p1 += __shfl_xor(p1, m, 64);
                p2 += __shfl_xor(p2, m, 64);
            }
            if (tx == 0){
                O1k[rowBase + 2*ty + rr] = p1;
                O2k[rowBase + 2*ty + rr] = p2;
            }
        }
    } else if (MODE == 2){
        #pragma unroll
        for (int rr = 0; rr < 2; ++rr){
            const size_t off = (size_t)(rowBase + 2*ty + rr)*128 + c0;
            *(float4*)&C[off]   = make_float4(acc[rr][0],acc[rr][1],acc[rr][2],acc[rr][3]);
            *(float4*)&C[off+4] = make_float4(acc[rr][4],acc[rr][5],acc[rr][6],acc[rr][7]);
        }
    } else { // MODE 5 (overwrite) / MODE 3 (accumulate)
        #pragma unroll
        for (int rr = 0; rr < 2; ++rr){
            const size_t off = (size_t)(rowBase + 2*ty + rr)*128 + c0;
            float u[8];
            #pragma unroll
            for (int j = 0; j < 8; ++j) u[j] = 0.5f*eluf(acc[rr][j]);
            if (MODE == 3){
                float4 pa = *(const float4*)&C[off];
                float4 pb = *(const float4*)&C[off+4];
                u[0]+=pa.x; u[1]+=pa.y; u[2]+=pa.z; u[3]+=pa.w;
                u[4]+=pb.x; u[5]+=pb.y; u[6]+=pb.z; u[7]+=pb.w;
            }
            *(float4*)&C[off]   = make_float4(u[0],u[1],u[2],u[3]);
            *(float4*)&C[off+4] = make_float4(u[4],u[5],u[6],u[7]);
        }
    }
}

// ---------- sort (both k): per-(k,b) bitonic + scalar prefix scans + E/F ----------
__global__ __launch_bounds__(1024) void k_sort(
    const float* __restrict__ s2k,
    float* __restrict__ s2s, int* __restrict__ perm,
    float* __restrict__ SEx, float* __restrict__ SFx,
    float* __restrict__ Eo, float* __restrict__ Fo,
    float* __restrict__ M2b)
{
    __shared__ float val[2048];
    __shared__ int   idx[2048];
    __shared__ float sa[2048], sb[2048], fa[2048], fb[2048];
    const int k = blockIdx.x >> 3, b = blockIdx.x & 7;
    const int t = threadIdx.x;
    const float* s2g = s2k + (size_t)k*ROWS + b*2048;
    float* s2so = s2s + k*16384 + b*2048;
    int*   permo = perm + k*16384 + b*2048;
    float* SExo = SEx + k*16392 + b*2049;
    float* SFxo = SFx + k*16392 + b*2049;
    float* Eok = Eo + (size_t)k*ROWS + b*2048;
    float* Fok = Fo + (size_t)k*ROWS + b*2048;

    for (int c = t; c < 2048; c += 1024){ val[c] = -s2g[c]; idx[c] = c; }
    __syncthreads();
    for (int kk = 2; kk <= 2048; kk <<= 1)
        for (int jj = kk >> 1; jj > 0; jj >>= 1){
            for (int c = t; c < 2048; c += 1024){
                int ixj = c ^ jj;
                if (ixj > c){
                    bool up = ((c & kk) == 0);
                    float av = val[c], bv = val[ixj];
                    if ((av > bv) == up){
                        val[c] = bv; val[ixj] = av;
                        int ia = idx[c]; idx[c] = idx[ixj]; idx[ixj] = ia;
                    }
                }
            }
            __syncthreads();
        }
    const float M2 = -val[0];
    for (int c = t; c < 2048; c += 1024){
        float sv = -val[c] - M2;
        sa[c] = expf(sv);
        fa[c] = expf(0.01f * sv);
    }
    __syncthreads();
    float *ss = sa, *sd = sb, *fs = fa, *fd = fb;
    for (int d = 1; d < 2048; d <<= 1){
        for (int c = t; c < 2048; c += 1024){
            sd[c] = ss[c] + (c >= d ? ss[c-d] : 0.f);
            fd[c] = fs[c] + (c >= d ? fs[c-d] : 0.f);
        }
        __syncthreads();
        float* tmp = ss; ss = sd; sd = tmp;
        tmp = fs; fs = fd; fd = tmp;
    }
    if (t == 0){ SExo[0] = 0.f; SFxo[0] = 0.f; M2b[k*8 + b] = M2; }
    for (int c = t; c < 2048; c += 1024){
        s2so[c]  = -val[c];
        permo[c] = idx[c];
        SExo[c + 1] = ss[c];
        SFxo[c + 1] = fs[c];
        float dv = s2g[c] - M2;
        Eok[c] = expf(dv);
        Fok[c] = expf(0.01f * dv);
    }
}

// ---------- chunk-local exclusive prefix (chunk=32, LDS-staged gather indices) ----------
__global__ __launch_bounds__(256) void k_scanA(
    const float* __restrict__ h, const int* __restrict__ perm,
    const float* __restrict__ Eo, const float* __restrict__ Fo,
    float* __restrict__ PEc, float* __restrict__ PFc,
    float* __restrict__ PEt, float* __restrict__ PFt)
{
    __shared__ int js[CH];
    __shared__ float wE[CH], wF[CH];
    const int b = blockIdx.x, ch = blockIdx.y;
    const int t = threadIdx.x;
    const int c0 = ch * CH;
    if (t < CH) js[t] = perm[b*2048 + c0 + t];
    __syncthreads();
    if (t < CH) wE[t] = Eo[b*2048 + js[t]];
    else if (t < 2*CH) wF[t-CH] = Fo[b*2048 + js[t-CH]];
    __syncthreads();
    const bool isF = t >= 128;
    const int d = t & 127;
    const float* wv = isF ? wF : wE;
    float* Pc = isF ? PFc : PEc;
    float* Pt = isF ? PFt : PEt;
    float acc = 0.f;
    #pragma unroll
    for (int i = 0; i < CH; ++i){
        float hv = h[(size_t)(b*2048 + js[i])*128 + d];
        Pc[(size_t)(b*2048 + c0 + i)*128 + d] = acc;
        acc += wv[i] * hv;
    }
    Pt[(b*NCH + ch)*128 + d] = acc;
}

// ---------- chunk offsets ----------
__global__ __launch_bounds__(256) void k_scanB(
    const float* __restrict__ PEt, const float* __restrict__ PFt,
    float* __restrict__ PEo, float* __restrict__ PFo)
{
    const int b = blockIdx.x, t = threadIdx.x;
    const bool isF = t >= 128;
    const int d = t & 127;
    const float* Pt = isF ? PFt : PEt;
    float* Po = isF ? PFo : PEo;
    float acc = 0.f;
    Po[(b*(NCH+1))*128 + d] = 0.f;
    #pragma unroll
    for (int ch = 0; ch < NCH; ++ch){
        acc += Pt[(b*NCH + ch)*128 + d];
        Po[(b*(NCH+1) + ch + 1)*128 + d] = acc;
    }
}

// ---------- attn pre: attentioned -> LN2 -> n ; store A/Z, B/Z ----------
__global__ __launch_bounds__(256) void k_attn_pre(
    const float* __restrict__ x, const float* __restrict__ s1g,
    const float* __restrict__ s2s, const float* __restrict__ SEx, const float* __restrict__ SFx,
    const float* __restrict__ PEc, const float* __restrict__ PFc,
    const float* __restrict__ PEo, const float* __restrict__ PFo,
    const float* __restrict__ M2b,
    const float* __restrict__ g2, const float* __restrict__ b2,
    float* __restrict__ nout, float* __restrict__ Ap, float* __restrict__ Bp)
{
    const int tid = threadIdx.x;
    const int wv = tid >> 6, lane = tid & 63;
    const int row = blockIdx.x * 4 + wv;
    const int b = row >> 11;
    const float s1v = s1g[row];
    const float M2 = M2b[b];
    const float t0 = s1v + M2;
    const float m  = (t0 >= 0.f) ? t0 : 0.01f*t0;
    const float A  = expf(t0 - m);
    const float B  = expf(0.01f*t0 - m);
    int lo = 0, hi = 2048;
    while (lo < hi){
        int mid = (lo + hi) >> 1;
        if (s2s[b*2048 + mid] >= -s1v) lo = mid + 1; else hi = mid;
    }
    const int c = lo;
    const float ZE  = SEx[b*2049 + c];
    const float ZF  = SFx[b*2049 + c];
    const float ZFt = SFx[b*2049 + 2048];
    const float Z = A*ZE + B*(ZFt - ZF);
    if (lane == 0){ Ap[row] = A / Z; Bp[row] = B / Z; }
    const float rz = 1.f / Z;
    const int ch = c >> 5;
    const int d0 = lane, d1 = lane + 64;
    float pe0 = PEo[(b*(NCH+1) + ch)*128 + d0], pe1 = PEo[(b*(NCH+1) + ch)*128 + d1];
    float pf0 = PFo[(b*(NCH+1) + ch)*128 + d0], pf1 = PFo[(b*(NCH+1) + ch)*128 + d1];
    if (c < 2048){
        pe0 += PEc[(size_t)(b*2048 + c)*128 + d0];
        pe1 += PEc[(size_t)(b*2048 + c)*128 + d1];
        pf0 += PFc[(size_t)(b*2048 + c)*128 + d0];
        pf1 += PFc[(size_t)(b*2048 + c)*128 + d1];
    }
    const float pft0 = PFo[(b*(NCH+1) + NCH)*128 + d0], pft1 = PFo[(b*(NCH+1) + NCH)*128 + d1];
    float a0 = (A*pe0 + B*(pft0 - pf0))*rz + x[row*128 + d0];
    float a1 = (A*pe1 + B*(pft1 - pf1))*rz + x[row*128 + d1];
    float s = a0 + a1;
    #pragma unroll
    for (int mm = 32; mm; mm >>= 1) s += __shfl_xor(s, mm, 64);
    float mean = s * (1.f/128.f);
    float c0v = a0 - mean, c1v = a1 - mean;
    float q = c0v*c0v + c1v*c1v;
    #pragma unroll
    for (int mm = 32; mm; mm >>= 1) q += __shfl_xor(q, mm, 64);
    float rstd = rsqrtf(q * (1.f/128.f) + EPS);
    nout[row*128 + d0] = c0v*rstd*g2[d0] + b2[d0];
    nout[row*128 + d1] = c1v*rstd*g2[d1] + b2[d1];
}

// ---------- agg ----------
__global__ __launch_bounds__(256) void k_agg(
    const float* __restrict__ s1_0, const float* __restrict__ s2_0,
    const float* __restrict__ E0, const float* __restrict__ F0,
    const float* __restrict__ Ap0, const float* __restrict__ Bp0,
    const float* __restrict__ s1_1, const float* __restrict__ s2_1,
    const float* __restrict__ E1, const float* __restrict__ F1,
    const float* __restrict__ Ap1, const float* __restrict__ Bp1,
    float* __restrict__ agg)
{
    __shared__ __align__(16) float s2a[2048], ea[2048], fa[2048];
    __shared__ __align__(16) float s2b[2048], eb[2048], fb[2048];
    const int b = blockIdx.x >> 6;
    const int tile = blockIdx.x & 63;
    const int t = threadIdx.x;
    for (int j = t; j < 2048; j += 256){
        s2a[j] = s2_0[b*2048 + j]; ea[j] = E0[b*2048 + j]; fa[j] = F0[b*2048 + j];
        s2b[j] = s2_1[b*2048 + j]; eb[j] = E1[b*2048 + j]; fb[j] = F1[b*2048 + j];
    }
    __syncthreads();
    for (int r = 0; r < 32; ++r){
        const int i = tile*32 + r;
        const int row = b*2048 + i;
        const float pa = Ap0[row], pb = Bp0[row], sa1 = s1_0[row];
        const float qa = Ap1[row], qb = Bp1[row], sb1 = s1_1[row];
        float4* outp = (float4*)(agg + (size_t)row * 2048);
        for (int j4 = t; j4 < 512; j4 += 256){
            float4 va  = ((const float4*)s2a)[j4];
            float4 vea = ((const float4*)ea )[j4];
            float4 vfa = ((const float4*)fa )[j4];
            float4 vb  = ((const float4*)s2b)[j4];
            float4 veb = ((const float4*)eb )[j4];
            float4 vfb = ((const float4*)fb )[j4];
            float4 o;
            o.x = 0.5f*(((sa1+va.x >= 0.f) ? pa*vea.x : pb*vfa.x) + ((sb1+vb.x >= 0.f) ? qa*veb.x : qb*vfb.x));
            o.y = 0.5f*(((sa1+va.y >= 0.f) ? pa*vea.y : pb*vfa.y) + ((sb1+vb.y >= 0.f) ? qa*veb.y : qb*vfb.y));
            o.z = 0.5f*(((sa1+va.z >= 0.f) ? pa*vea.z : pb*vfa.z) + ((sb1+vb.z >= 0.f) ? qa*veb.z : qb*vfb.z));
            o.w = 0.5f*(((sa1+va.w >= 0.f) ? pa*vea.w : pb*vfa.w) + ((sb1+vb.w >= 0.f) ? qa*veb.w : qb*vfb.w));
            outp[j4] = o;
        }
    }
}

// ---------- launch ----------
extern "C" void kernel_launch(void* const* d_in, const int* in_sizes, int n_in,
                              void* d_out, int out_size, void* d_ws, size_t ws_size,
                              hipStream_t stream)
{
    const float* xin  = (const float*)d_in[0];
    const float* enc  = (const float*)d_in[1];
    const float* Wenc = (const float*)d_in[2];
    const float* benc = (const float*)d_in[3];
    const float* g1   = (const float*)d_in[4];
    const float* b1   = (const float*)d_in[5];
    const float* g2   = (const float*)d_in[6];
    const float* b2   = (const float*)d_in[7];
    const float* ff0  = (const float*)d_in[8];
    const float* ff1  = (const float*)d_in[9];
    const float* aw   = (const float*)d_in[10];

    float* out = (float*)d_out;
    float* agg = out + (size_t)ROWS * 128;

    const size_t R = ROWS, RD = (size_t)ROWS * 128;
    float* ws  = (float*)d_ws;
    float* Wt  = ws;                 // 5*16384
    float* x   = Wt + 5*16384;       // RD
    float* xn  = x + RD;             // RD
    float* h   = xn + RD;            // RD (doubles as LN2-output buffer)
    float* PEc = h + RD;             // RD
    float* PFc = PEc + RD;           // RD
    float* PEt = PFc + RD;           // 8*64*128
    float* PFt = PEt + 8*NCH*128;
    float* PEo = PFt + 8*NCH*128;    // 8*65*128
    float* PFo = PEo + 8*(NCH+1)*128;
    float* s2s = PFo + 8*(NCH+1)*128; // 2*8*2048
    int*   perm = (int*)(s2s + 2*16384);
    float* SEx = (float*)(perm + 2*16384);  // 2*8*2049
    float* SFx = SEx + 2*16392;
    float* M2b = SFx + 2*16392;      // 16
    float* s1k = M2b + 16;           // [2][R]
    float* s2k = s1k + 2*R;
    float* Ek  = s2k + 2*R;
    float* Fk  = Ek + 2*R;
    float* Apk = Fk + 2*R;
    float* Bpk = Apk + 2*R;
    // total ≈ 11,159,600 floats = 42.6 MiB

    k_transpose<<<80, 256, 0, stream>>>(Wenc, ff0, ff1, Wt);

    k_gemm<0><<<ROWS/32, 256, 0, stream>>>(enc, Wt, x, xin, benc, g1, b1, xn, nullptr);

    // both k: h (k=0 only) + s1/s2, one dispatch, grid.y selects k
    k_gemm<6><<<dim3(ROWS/32, 2), 256, 0, stream>>>(xn, Wt + 16384, h,
                                                    nullptr, aw, nullptr, nullptr,
                                                    s1k, s2k);

    k_sort<<<16, 1024, 0, stream>>>(s2k, s2s, perm, SEx, SFx, Ek, Fk, M2b);

    for (int k = 0; k < 2; ++k){
        if (k == 1)  // recompute h1 into shared h buffer
            k_gemm<2><<<ROWS/32, 256, 0, stream>>>(xn, Wt + 2*16384, h,
                                                   nullptr, nullptr, nullptr, nullptr,
                                                   nullptr, nullptr);
        k_scanA<<<dim3(BSZ, NCH), 256, 0, stream>>>(h, perm + k*16384,
                                                    Ek + k*R, Fk + k*R,
                                                    PEc, PFc, PEt, PFt);
        k_scanB<<<BSZ, 256, 0, stream>>>(PEt, PFt, PEo, PFo);
        // LN2 output written into h (h's old contents are dead by now)
        k_attn_pre<<<ROWS/4, 256, 0, stream>>>(x, s1k + k*R, s2s + k*16384,
                                               SEx + k*16392, SFx + k*16392,
                                               PEc, PFc, PEo, PFo, M2b + k*8,
                                               g2, b2, h, Apk + k*R, Bpk + k*R);
        if (k == 0)
            k_gemm<5><<<ROWS/32, 256, 0, stream>>>(h, Wt + 3*16384, out,
                                                   nullptr, nullptr, nullptr, nullptr,
                                                   nullptr, nullptr);
        else
            k_gemm<3><<<ROWS/32, 256, 0, stream>>>(h, Wt + 4*16384, out,
                                                   nullptr, nullptr, nullptr, nullptr,
                                                   nullptr, nullptr);
    }

    k_agg<<<BSZ*64, 256, 0, stream>>>(s1k, s2k, Ek, Fk, Apk, Bpk,
                                      s1k + R, s2k + R, Ek + R, Fk + R, Apk + R, Bpk + R,
                                      agg);
}